// Round 3
// baseline (119.749 us; speedup 1.0000x reference)
//
#include <hip/hip_runtime.h>
#include <hip/hip_bf16.h>

#define BATCH   8
#define NODES   8192
#define CH      128            // CH_IN == CH_OUT
#define NEXP    64
#define TN      16             // nodes per tile (tile M = 8*16 = 128 rows)
#define MAXP    (NODES + NEXP * TN)   // padded sorted-list capacity = 9216
#define NTILES  (MAXP / TN)           // 576 tiles; gemm uses 2 blocks/tile

typedef __attribute__((ext_vector_type(8))) short bf16x8;  // 8 bf16 = 4 VGPRs
typedef __attribute__((ext_vector_type(4))) float f32x4;

__device__ __forceinline__ short f2bf(float f) {
    union { float f; unsigned u; } v; v.f = f;
    unsigned r = (v.u + 0x7fffu + ((v.u >> 16) & 1u)) >> 16;   // RNE
    return (short)r;
}

__device__ __forceinline__ bf16x8 cvt8(f32x4 lo, f32x4 hi) {
    bf16x8 r;
    r[0] = f2bf(lo[0]); r[1] = f2bf(lo[1]); r[2] = f2bf(lo[2]); r[3] = f2bf(lo[3]);
    r[4] = f2bf(hi[0]); r[5] = f2bf(hi[1]); r[6] = f2bf(hi[2]); r[7] = f2bf(hi[3]);
    return r;
}

// ---------------------------------------------------------------------------
// Prep: 64 blocks; block e converts W[e] -> bf16, counting-sorts its node
// segment (padded to TN), and writes texp[tile] = expert id (-1 for unused
// tiles). Padded prefix sum via wave-0 __shfl_up scan (was a serial 64-iter
// loop: ~3.5 us -> ~0.2 us).
// ---------------------------------------------------------------------------
__global__ __launch_bounds__(256)
void prep_kernel(const int* __restrict__ sel, const float* __restrict__ W,
                 short* __restrict__ Wbf, int* __restrict__ sorted,
                 int* __restrict__ texp)
{
    const int e = blockIdx.x;
    const int t = threadIdx.x;

    // (a) W[e] fp32 -> bf16 (read-once: nontemporal)
    {
        const float* ws = W   + (size_t)e * CH * CH;
        short*       wd = Wbf + (size_t)e * CH * CH;
        #pragma unroll
        for (int i = 0; i < 8; ++i) {
            int idx = (i * 256 + t) * 8;
            f32x4 lo = __builtin_nontemporal_load(reinterpret_cast<const f32x4*>(ws + idx));
            f32x4 hi = __builtin_nontemporal_load(reinterpret_cast<const f32x4*>(ws + idx + 4));
            *reinterpret_cast<bf16x8*>(wd + idx) = cvt8(lo, hi);
        }
    }

    // (b) histogram of all of sel (L2-hot, 32 KB)
    __shared__ int cnt[NEXP];
    __shared__ int s_off, s_cnt, cursor;
    if (t < NEXP) cnt[t] = 0;
    if (t == 0) cursor = 0;
    __syncthreads();

    int myv[NODES / 256];
    #pragma unroll
    for (int i = 0; i < NODES / 256; ++i) {
        myv[i] = sel[i * 256 + t];
        atomicAdd(&cnt[myv[i]], 1);
    }
    __syncthreads();

    // padded exclusive prefix via wave-0 shuffle scan
    if (t < NEXP) {
        int c = cnt[t];
        int p = (c + TN - 1) & ~(TN - 1);
        int s = p;
        #pragma unroll
        for (int d = 1; d < NEXP; d <<= 1) {
            int o = __shfl_up(s, d, 64);
            if (t >= d) s += o;
        }
        if (t == e) { s_off = s - p; s_cnt = c; }
    }
    __syncthreads();

    const int off = s_off, myc = s_cnt;
    const int pad = (myc + TN - 1) & ~(TN - 1);

    for (int i = myc + t; i < pad; i += 256) sorted[off + i] = -1;
    for (int i = off / TN + t; i < (off + pad) / TN; i += 256) texp[i] = e;
    if (e == NEXP - 1) {       // tail tiles beyond the grand total
        for (int i = (off + pad) / TN + t; i < NTILES; i += 256) texp[i] = -1;
    }

    #pragma unroll
    for (int i = 0; i < NODES / 256; ++i) {
        if (myv[i] == e) {
            int pos = atomicAdd(&cursor, 1);
            sorted[off + pos] = i * 256 + t;
        }
    }
}

// ---------------------------------------------------------------------------
// GEMM: 2 blocks per tile (M-split), 128 threads = 2 waves each. Block does
// 64 rows (8 nodes x 8 batches) x N=128 x K=128 with mfma_f32_16x16x32_bf16.
// 1152 blocks -> 4.5 blocks/CU (tail waste ~11% vs 33% at 576x256).
// x loads / out stores nontemporal (touched once); Wbf stays L1/L2-hot.
// ---------------------------------------------------------------------------
__global__ __launch_bounds__(128)
void gemm_kernel(const float* __restrict__ x, const short* __restrict__ Wbf,
                 float* __restrict__ out, const int* __restrict__ sorted,
                 const int* __restrict__ texp)
{
    __shared__ int s_nodes[8];
    __shared__ int s_e;

    const int tid  = threadIdx.x;
    const int tile = blockIdx.x >> 1;
    const int half = blockIdx.x & 1;

    if (tid < 8) s_nodes[tid] = sorted[tile * TN + half * 8 + tid];
    if (tid == 0) s_e = texp[tile];
    __syncthreads();

    const int e = s_e;
    if (e < 0) return;                 // unused tile
    if (s_nodes[0] < 0) return;        // all-pad half (pads are trailing)

    const int wave = tid >> 6;         // 0..1
    const int lane = tid & 63;
    const int m16  = lane & 15;
    const int quad = lane >> 4;        // k-subchunk (A/B) / row group (D)

    const float* xrow[2];
    #pragma unroll
    for (int rt = 0; rt < 2; ++rt) {
        int r    = wave * 32 + rt * 16 + m16;      // row within this half (0..63)
        int node = s_nodes[r >> 3];
        int b    = r & 7;
        int nd   = (node >= 0) ? node : 0;         // safe address for pads
        xrow[rt] = x + ((size_t)(b * NODES + nd)) * CH;
    }
    const short* wbase = Wbf + (size_t)e * CH * CH;

    f32x4 acc[2][8];
    #pragma unroll
    for (int rt = 0; rt < 2; ++rt)
        #pragma unroll
        for (int ct = 0; ct < 8; ++ct)
            acc[rt][ct] = (f32x4){0.f, 0.f, 0.f, 0.f};

    #pragma unroll
    for (int kk = 0; kk < 4; ++kk) {
        const int k0 = kk * 32 + quad * 8;

        bf16x8 afrag[2];
        #pragma unroll
        for (int rt = 0; rt < 2; ++rt) {
            const f32x4* p = reinterpret_cast<const f32x4*>(xrow[rt] + k0);
            f32x4 lo = __builtin_nontemporal_load(p);
            f32x4 hi = __builtin_nontemporal_load(p + 1);
            afrag[rt] = cvt8(lo, hi);
        }

        #pragma unroll
        for (int ct = 0; ct < 8; ++ct) {
            bf16x8 bfrag = *reinterpret_cast<const bf16x8*>(
                wbase + (size_t)(ct * 16 + m16) * CH + k0);  // B[k][n]=W[n][k]
            acc[0][ct] = __builtin_amdgcn_mfma_f32_16x16x32_bf16(
                             afrag[0], bfrag, acc[0][ct], 0, 0, 0);
            acc[1][ct] = __builtin_amdgcn_mfma_f32_16x16x32_bf16(
                             afrag[1], bfrag, acc[1][ct], 0, 0, 0);
        }
    }

    // D layout: col = lane&15, row = quad*4 + reg
    #pragma unroll
    for (int rt = 0; rt < 2; ++rt) {
        #pragma unroll
        for (int reg = 0; reg < 4; ++reg) {
            int r    = wave * 32 + rt * 16 + quad * 4 + reg;
            int node = s_nodes[r >> 3];
            if (node < 0) continue;              // padded row: drop
            int b = r & 7;
            float* orow = out + ((size_t)(b * NODES + node)) * CH;
            #pragma unroll
            for (int ct = 0; ct < 8; ++ct)
                __builtin_nontemporal_store(acc[rt][ct][reg], orow + ct * 16 + m16);
        }
    }
}

extern "C" void kernel_launch(void* const* d_in, const int* in_sizes, int n_in,
                              void* d_out, int out_size, void* d_ws, size_t ws_size,
                              hipStream_t stream)
{
    const float* x   = (const float*)d_in[0];
    const int*   sel = (const int*)  d_in[1];
    const float* W   = (const float*)d_in[2];
    float*       out = (float*)d_out;

    short* Wbf    = (short*)d_ws;                                        // 2 MiB
    int*   sorted = (int*)((char*)d_ws + (size_t)NEXP * CH * CH * sizeof(short));
    int*   texp   = sorted + MAXP;

    prep_kernel<<<NEXP, 256, 0, stream>>>(sel, W, Wbf, sorted, texp);
    gemm_kernel<<<NTILES * 2, 128, 0, stream>>>(x, Wbf, out, sorted, texp);
}